// Round 3
// baseline (26.326 us; speedup 1.0000x reference)
//
#include <hip/hip_runtime.h>

// RoPE: out[..., 2j]   = cos(a)*x[...,2j] - sin(a)*x[...,2j+1]
//       out[..., 2j+1] = sin(a)*x[...,2j] + cos(a)*x[...,2j+1]
// a = pos * theta^(-2j/d_k),  d_k = 128, theta = 10000.
//
// Memory-bound: 64 MB read + 64 MB write, HBM floor ~20.5 us. R2 ran 26.1 us
// (4.95 TB/s, 79% of copy ceiling) with 1 load in flight per iteration —
// latency coverage was marginal. This version batches IPT=4 independent
// loads per thread (all issued before any use) for 4x memory-level
// parallelism, with a compile-time trip count so the unroll is total.
//
// Trig via v_sin_f32/v_cos_f32 (input in REVOLUTIONS): fold 1/(2*pi) into the
// frequency constant, range-reduce with v_fract_f32 (rev >= 0 always).
// NOTE: __exp2f/__sincosf clash with glibc math.h in the host pass — use
// exp2f + __builtin_amdgcn_* instead.

constexpr float LOG2_THETA = 13.28771237954945f;  // log2(10000)
constexpr float LOG2_2PI   = 2.6514961294723187f; // log2(2*pi)

constexpr int BLOCK = 256;
constexpr int IPT = 4;  // float4s per thread; 4 x-loads + 4 pos-loads in flight

__global__ __launch_bounds__(BLOCK)
void rope_f32_ipt4(const float* __restrict__ x,
                   const int* __restrict__ pos,
                   float* __restrict__ out,
                   int stride /* = total threads, multiple of 32 */) {
    const int tid = blockIdx.x * BLOCK + threadIdx.x;

    // float4 index within the 128-wide row: same for all IPT items because
    // stride % 32 == 0.
    const int q = tid & 31;
    const int j0 = 2 * q;
    // f[j] = theta^(-2j/128) / (2*pi)
    const float f0 = exp2f(-(float)(2 * j0)       * (LOG2_THETA / 128.0f) - LOG2_2PI);
    const float f1 = exp2f(-(float)(2 * (j0 + 1)) * (LOG2_THETA / 128.0f) - LOG2_2PI);

    const float4* __restrict__ xv = reinterpret_cast<const float4*>(x);
    float4* __restrict__ ov = reinterpret_cast<float4*>(out);

    // Batch-issue all loads first: 8 independent VMEM ops in flight per lane.
    float4 v[IPT];
    int pr[IPT];
#pragma unroll
    for (int k = 0; k < IPT; ++k) {
        const int i = tid + k * stride;
        v[k] = xv[i];
        pr[k] = pos[i >> 5];  // 32 float4 per d_k=128 row
    }

#pragma unroll
    for (int k = 0; k < IPT; ++k) {
        const float p = (float)pr[k];
        const float r0 = __builtin_amdgcn_fractf(p * f0);  // revolutions in [0,1)
        const float r1 = __builtin_amdgcn_fractf(p * f1);
        const float s0 = __builtin_amdgcn_sinf(r0);
        const float c0 = __builtin_amdgcn_cosf(r0);
        const float s1 = __builtin_amdgcn_sinf(r1);
        const float c1 = __builtin_amdgcn_cosf(r1);

        const float4 a = v[k];
        float4 r;
        r.x = c0 * a.x - s0 * a.y;
        r.y = s0 * a.x + c0 * a.y;
        r.z = c1 * a.z - s1 * a.w;
        r.w = s1 * a.z + c1 * a.w;
        ov[tid + k * stride] = r;
    }
}

// Fallback for sizes not divisible by BLOCK*IPT (not expected here).
__global__ __launch_bounds__(BLOCK)
void rope_f32_generic(const float* __restrict__ x,
                      const int* __restrict__ pos,
                      float* __restrict__ out,
                      int n_vec4) {
    const int stride = gridDim.x * BLOCK;
    const int i0 = blockIdx.x * BLOCK + threadIdx.x;
    const int q = i0 & 31;
    const int j0 = 2 * q;
    const float f0 = exp2f(-(float)(2 * j0)       * (LOG2_THETA / 128.0f) - LOG2_2PI);
    const float f1 = exp2f(-(float)(2 * (j0 + 1)) * (LOG2_THETA / 128.0f) - LOG2_2PI);

    const float4* __restrict__ xv = reinterpret_cast<const float4*>(x);
    float4* __restrict__ ov = reinterpret_cast<float4*>(out);

    for (int i = i0; i < n_vec4; i += stride) {
        const float4 a = xv[i];
        const float p = (float)pos[i >> 5];
        const float r0 = __builtin_amdgcn_fractf(p * f0);
        const float r1 = __builtin_amdgcn_fractf(p * f1);
        const float s0 = __builtin_amdgcn_sinf(r0);
        const float c0 = __builtin_amdgcn_cosf(r0);
        const float s1 = __builtin_amdgcn_sinf(r1);
        const float c1 = __builtin_amdgcn_cosf(r1);
        float4 r;
        r.x = c0 * a.x - s0 * a.y;
        r.y = s0 * a.x + c0 * a.y;
        r.z = c1 * a.z - s1 * a.w;
        r.w = s1 * a.z + c1 * a.w;
        ov[i] = r;
    }
}

extern "C" void kernel_launch(void* const* d_in, const int* in_sizes, int n_in,
                              void* d_out, int out_size, void* d_ws, size_t ws_size,
                              hipStream_t stream) {
    const float* x = (const float*)d_in[0];
    const int* pos = (const int*)d_in[1];
    float* out = (float*)d_out;

    const int n = in_sizes[0];  // B*S*DK = 16*8192*128
    const int n_vec4 = n / 4;   // 4,194,304

    if (n_vec4 % (BLOCK * IPT) == 0) {
        const int total_threads = n_vec4 / IPT;   // 1,048,576
        const int grid = total_threads / BLOCK;   // 4096
        // stride = total_threads is a multiple of 32 (row-invariant q holds)
        rope_f32_ipt4<<<grid, BLOCK, 0, stream>>>(x, pos, out, total_threads);
    } else {
        int grid = (n_vec4 + BLOCK - 1) / BLOCK;
        if (grid > 2048) grid = 2048;
        rope_f32_generic<<<grid, BLOCK, 0, stream>>>(x, pos, out, n_vec4);
    }
}